// Round 1
// baseline (9133.355 us; speedup 1.0000x reference)
//
#include <hip/hip_runtime.h>
#include <hip/hip_bf16.h>

typedef __bf16 bf16x8 __attribute__((ext_vector_type(8)));
typedef float f32x4 __attribute__((ext_vector_type(4)));

#define MFMA_B16(a,b,c) __builtin_amdgcn_mfma_f32_16x16x32_bf16((a),(b),(c),0,0,0)

// Tsit5 coefficients
#define A21f 0.161f
#define A31f (-0.008480655492356989f)
#define A32f 0.335480655492357f
#define A41f 2.8971530571054935f
#define A42f (-6.359448489975075f)
#define A43f 4.3622954328695815f
#define A51f 5.325864828439257f
#define A52f (-11.748883564062828f)
#define A53f 7.4955393428898365f
#define A54f (-0.09249506636175525f)
#define A61f 5.86145544294642f
#define A62f (-12.92096931784711f)
#define A63f 8.159367898576159f
#define A64f (-0.071584973281401f)
#define A65f (-0.028269050394068383f)
#define B1f 0.09646076681806523f
#define B2f 0.01f
#define B3f 0.4798896504144996f
#define B4f 1.379008574103742f
#define B5f (-3.290069515436081f)
#define B6f 2.324710524099774f

constexpr int T_SAVE = 128;
constexpr int DIM = 64;
constexpr int HID = 256;

__device__ __forceinline__ float fast_exp2(float x){
#if __has_builtin(__builtin_amdgcn_exp2f)
  return __builtin_amdgcn_exp2f(x);
#else
  return exp2f(x);
#endif
}
__device__ __forceinline__ float fast_rcp(float x){
#if __has_builtin(__builtin_amdgcn_rcpf)
  return __builtin_amdgcn_rcpf(x);
#else
  return 1.0f / x;
#endif
}
__device__ __forceinline__ float tanh_fast(float x){
  // tanh(x) = 1 - 2/(exp2(2*log2e*x)+1); saturates correctly for large |x|
  float t = fast_exp2(x * 2.8853900817779268f);
  return 1.0f - 2.0f * fast_rcp(t + 1.0f);
}

__global__ __launch_bounds__(256, 1)
void node_tsit5_kernel(const float* __restrict__ y0, const float* __restrict__ ts,
                       const float* __restrict__ W1g, const float* __restrict__ b1g,
                       const float* __restrict__ W2g, const float* __restrict__ b2g,
                       const int* __restrict__ nsub_p, float* __restrict__ out)
{
  const int tid = (int)threadIdx.x;
  const int w   = tid >> 6;   // wave 0..3
  const int l   = tid & 63;   // lane
  const int c   = l & 15;
  const int g   = l >> 4;
  const int rowbase = (int)blockIdx.x * 16;

  // fragment-ordered bf16 staging buffers: [ks][phys(lane)][j]
  __shared__ __align__(16) __bf16 Yh[2*64*8];
  __shared__ __align__(16) __bf16 Yl[2*64*8];
  __shared__ __align__(16) __bf16 Hh[8*64*8];
  __shared__ __align__(16) __bf16 Hl[8*64*8];
  __shared__ float ts_s[T_SAVE];

  if (tid < T_SAVE) ts_s[tid] = ts[tid];

  const int nsub = nsub_p[0];

  // ---- weight fragments, pre-split into (hi, lo) bf16, held in registers ----
  bf16x8 w1h[4][2], w1l[4][2], w2h[8], w2l[8];
#pragma unroll
  for (int nt = 0; nt < 4; ++nt)
#pragma unroll
    for (int ks = 0; ks < 2; ++ks)
#pragma unroll
      for (int j = 0; j < 8; ++j) {
        float v = W1g[(ks*32 + g*8 + j)*HID + ((4*w+nt)*16 + c)];
        __bf16 hi = (__bf16)v;
        w1h[nt][ks][j] = hi;
        w1l[nt][ks][j] = (__bf16)(v - (float)hi);
      }
#pragma unroll
  for (int ks = 0; ks < 8; ++ks)
#pragma unroll
    for (int j = 0; j < 8; ++j) {
      float v = W2g[(ks*32 + g*8 + j)*DIM + (16*w + c)];
      __bf16 hi = (__bf16)v;
      w2h[ks][j] = hi;
      w2l[ks][j] = (__bf16)(v - (float)hi);
    }
  float b1v[4];
#pragma unroll
  for (int nt = 0; nt < 4; ++nt) b1v[nt] = b1g[(4*w+nt)*16 + c];
  const float b2v = b2g[16*w + c];

  const int d_    = 16*w + c;              // this lane's output dim
  const int physL = l ^ ((l >> 3) & 3);    // swizzled read chunk

  // precomputed swizzled element offsets for the lane's 4 (row,d) slots
  int yoff[4];
#pragma unroll
  for (int s = 0; s < 4; ++s) {
    int row = 4*g + s;
    int lp  = row | (((d_ >> 3) & 3) << 4);
    int ph  = lp ^ ((lp >> 3) & 3);
    yoff[s] = (d_ >> 5)*512 + ph*8 + (d_ & 7);
  }
  int hoff[4][4];
#pragma unroll
  for (int nt = 0; nt < 4; ++nt) {
    int jcol = (4*w+nt)*16 + c;
#pragma unroll
    for (int r = 0; r < 4; ++r) {
      int row = 4*g + r;
      int lp  = row | (((jcol >> 3) & 3) << 4);
      int ph  = lp ^ ((lp >> 3) & 3);
      hoff[nt][r] = (jcol >> 5)*512 + ph*8 + (jcol & 7);
    }
  }

  // ---- initial state: load y0 slots, emit t=0 ----
  float y[4];
#pragma unroll
  for (int s = 0; s < 4; ++s) {
    int row = rowbase + 4*g + s;
    y[s] = y0[row*DIM + d_];
    out[(size_t)row*(T_SAVE*DIM) + d_] = y[s];
  }
  __syncthreads();   // ts_s ready

  float k1[4], k2[4], k3[4], k4[4], k5[4], k6[4], ysv[4];
#pragma unroll
  for (int s = 0; s < 4; ++s) ysv[s] = y[s];

  // one evaluation of f(ysv) -> kout; ysv in C/D slot layout
  auto feval = [&](float (&kout)[4]) {
    // stage-input -> split bf16 -> fragment-ordered LDS
#pragma unroll
    for (int s = 0; s < 4; ++s) {
      __bf16 hi = (__bf16)ysv[s];
      Yh[yoff[s]] = hi;
      Yl[yoff[s]] = (__bf16)(ysv[s] - (float)hi);
    }
    __syncthreads();
    bf16x8 ah0 = *(const bf16x8*)&Yh[physL*8];
    bf16x8 ah1 = *(const bf16x8*)&Yh[512 + physL*8];
    bf16x8 al0 = *(const bf16x8*)&Yl[physL*8];
    bf16x8 al1 = *(const bf16x8*)&Yl[512 + physL*8];
    f32x4 acc[4];
#pragma unroll
    for (int nt = 0; nt < 4; ++nt) acc[nt] = f32x4{0.f,0.f,0.f,0.f};
    // 3-term split product: Ah*Bh + Ah*Bl + Al*Bh  (fp32 accumulate)
#pragma unroll
    for (int nt = 0; nt < 4; ++nt) acc[nt] = MFMA_B16(ah0, w1h[nt][0], acc[nt]);
#pragma unroll
    for (int nt = 0; nt < 4; ++nt) acc[nt] = MFMA_B16(ah1, w1h[nt][1], acc[nt]);
#pragma unroll
    for (int nt = 0; nt < 4; ++nt) acc[nt] = MFMA_B16(ah0, w1l[nt][0], acc[nt]);
#pragma unroll
    for (int nt = 0; nt < 4; ++nt) acc[nt] = MFMA_B16(ah1, w1l[nt][1], acc[nt]);
#pragma unroll
    for (int nt = 0; nt < 4; ++nt) acc[nt] = MFMA_B16(al0, w1h[nt][0], acc[nt]);
#pragma unroll
    for (int nt = 0; nt < 4; ++nt) acc[nt] = MFMA_B16(al1, w1h[nt][1], acc[nt]);
    // tanh + bias, split, scatter to H fragment buffer
#pragma unroll
    for (int nt = 0; nt < 4; ++nt)
#pragma unroll
      for (int r = 0; r < 4; ++r) {
        float th = tanh_fast(acc[nt][r] + b1v[nt]);
        __bf16 hi = (__bf16)th;
        Hh[hoff[nt][r]] = hi;
        Hl[hoff[nt][r]] = (__bf16)(th - (float)hi);
      }
    __syncthreads();
    f32x4 a2[6];
#pragma unroll
    for (int i = 0; i < 6; ++i) a2[i] = f32x4{0.f,0.f,0.f,0.f};
#pragma unroll
    for (int ks = 0; ks < 8; ++ks) {
      bf16x8 ah = *(const bf16x8*)&Hh[ks*512 + physL*8];
      bf16x8 al = *(const bf16x8*)&Hl[ks*512 + physL*8];
      const int p = (ks & 1) * 3;
      a2[p+0] = MFMA_B16(ah, w2h[ks], a2[p+0]);
      a2[p+1] = MFMA_B16(ah, w2l[ks], a2[p+1]);
      a2[p+2] = MFMA_B16(al, w2h[ks], a2[p+2]);
    }
#pragma unroll
    for (int s = 0; s < 4; ++s)
      kout[s] = ((a2[0][s]+a2[3][s]) + (a2[1][s]+a2[4][s])) + ((a2[2][s]+a2[5][s]) + b2v);
  };

  for (int iv = 0; iv < T_SAVE-1; ++iv) {
    const float h = (ts_s[iv+1] - ts_s[iv]) / (float)nsub;
    for (int sub = 0; sub < nsub; ++sub) {
      feval(k1);
#pragma unroll
      for (int s = 0; s < 4; ++s) ysv[s] = fmaf(h, A21f*k1[s], y[s]);
      feval(k2);
#pragma unroll
      for (int s = 0; s < 4; ++s) {
        float t = fmaf(A32f, k2[s], A31f*k1[s]);
        ysv[s] = fmaf(h, t, y[s]);
      }
      feval(k3);
#pragma unroll
      for (int s = 0; s < 4; ++s) {
        float t = A41f*k1[s];
        t = fmaf(A42f, k2[s], t);
        t = fmaf(A43f, k3[s], t);
        ysv[s] = fmaf(h, t, y[s]);
      }
      feval(k4);
#pragma unroll
      for (int s = 0; s < 4; ++s) {
        float t = A51f*k1[s];
        t = fmaf(A52f, k2[s], t);
        t = fmaf(A53f, k3[s], t);
        t = fmaf(A54f, k4[s], t);
        ysv[s] = fmaf(h, t, y[s]);
      }
      feval(k5);
#pragma unroll
      for (int s = 0; s < 4; ++s) {
        float t = A61f*k1[s];
        t = fmaf(A62f, k2[s], t);
        t = fmaf(A63f, k3[s], t);
        t = fmaf(A64f, k4[s], t);
        t = fmaf(A65f, k5[s], t);
        ysv[s] = fmaf(h, t, y[s]);
      }
      feval(k6);
#pragma unroll
      for (int s = 0; s < 4; ++s) {
        float t = B1f*k1[s];
        t = fmaf(B2f, k2[s], t);
        t = fmaf(B3f, k3[s], t);
        t = fmaf(B4f, k4[s], t);
        t = fmaf(B5f, k5[s], t);
        t = fmaf(B6f, k6[s], t);
        y[s] = fmaf(h, t, y[s]);
        ysv[s] = y[s];
      }
    }
#pragma unroll
    for (int s = 0; s < 4; ++s) {
      int row = rowbase + 4*g + s;
      out[(size_t)row*(T_SAVE*DIM) + (size_t)(iv+1)*DIM + d_] = y[s];
    }
  }
}

extern "C" void kernel_launch(void* const* d_in, const int* in_sizes, int n_in,
                              void* d_out, int out_size, void* d_ws, size_t ws_size,
                              hipStream_t stream) {
  const float* y0 = (const float*)d_in[0];
  const float* ts = (const float*)d_in[1];
  const float* W1 = (const float*)d_in[2];
  const float* b1 = (const float*)d_in[3];
  const float* W2 = (const float*)d_in[4];
  const float* b2 = (const float*)d_in[5];
  const int* nsub = (const int*)d_in[6];
  float* out = (float*)d_out;

  const int Bnum = in_sizes[0] / DIM;       // 4096
  const int nblocks = Bnum / 16;            // 256 workgroups, one per CU
  node_tsit5_kernel<<<nblocks, 256, 0, stream>>>(y0, ts, W1, b1, W2, b2, nsub, out);
}

// Round 2
// 7032.994 us; speedup vs baseline: 1.2986x; 1.2986x over previous
//
#include <hip/hip_runtime.h>
#include <hip/hip_bf16.h>

typedef __bf16 bf16x8 __attribute__((ext_vector_type(8)));
typedef float f32x4 __attribute__((ext_vector_type(4)));

#define MFMA_B16(a,b,c) __builtin_amdgcn_mfma_f32_16x16x32_bf16((a),(b),(c),0,0,0)

// Tsit5 coefficients
#define A21f 0.161f
#define A31f (-0.008480655492356989f)
#define A32f 0.335480655492357f
#define A41f 2.8971530571054935f
#define A42f (-6.359448489975075f)
#define A43f 4.3622954328695815f
#define A51f 5.325864828439257f
#define A52f (-11.748883564062828f)
#define A53f 7.4955393428898365f
#define A54f (-0.09249506636175525f)
#define A61f 5.86145544294642f
#define A62f (-12.92096931784711f)
#define A63f 8.159367898576159f
#define A64f (-0.071584973281401f)
#define A65f (-0.028269050394068383f)
#define B1f 0.09646076681806523f
#define B2f 0.01f
#define B3f 0.4798896504144996f
#define B4f 1.379008574103742f
#define B5f (-3.290069515436081f)
#define B6f 2.324710524099774f

constexpr int T_SAVE = 128;
constexpr int DIM = 64;
constexpr int HID = 256;

__device__ __forceinline__ float fast_exp2(float x){
#if __has_builtin(__builtin_amdgcn_exp2f)
  return __builtin_amdgcn_exp2f(x);
#else
  return exp2f(x);
#endif
}
__device__ __forceinline__ float fast_rcp(float x){
#if __has_builtin(__builtin_amdgcn_rcpf)
  return __builtin_amdgcn_rcpf(x);
#else
  return 1.0f / x;
#endif
}
__device__ __forceinline__ float tanh_fast(float x){
  float t = fast_exp2(x * 2.8853900817779268f);
  return 1.0f - 2.0f * fast_rcp(t + 1.0f);
}

// 8 waves / block, 16 batch rows / block.
// Layer1: wave w owns hidden tiles {2w, 2w+1}.
// Layer2: wave w owns output col-tile (w&3), K-half (w>>2); pair (w, w^4)
//         exchanges f32x4 partials through LDS (commutative add -> both waves
//         hold bitwise-identical k and replicate the y state).
__global__ __launch_bounds__(512, 2)
void node_tsit5_kernel(const float* __restrict__ y0, const float* __restrict__ ts,
                       const float* __restrict__ W1g, const float* __restrict__ b1g,
                       const float* __restrict__ W2g, const float* __restrict__ b2g,
                       const int* __restrict__ nsub_p, float* __restrict__ out)
{
  const int tid = (int)threadIdx.x;
  const int w   = tid >> 6;   // wave 0..7
  const int l   = tid & 63;   // lane
  const int c   = l & 15;
  const int g   = l >> 4;
  const int wq  = w & 3;      // pair id / output col-tile
  const int kh  = w >> 2;     // K-half for layer2
  const bool hiW = (kh == 0);
  const int rowbase = (int)blockIdx.x * 16;

  // fragment-ordered bf16 staging buffers (swizzled), + partial-exchange buf
  __shared__ __align__(16) __bf16 Yh[2*64*8];
  __shared__ __align__(16) __bf16 Yl[2*64*8];
  __shared__ __align__(16) __bf16 Hh[8*64*8];
  __shared__ __align__(16) __bf16 Hl[8*64*8];
  __shared__ __align__(16) f32x4 Pex[8*64];
  __shared__ float ts_s[T_SAVE];

  if (tid < T_SAVE) ts_s[tid] = ts[tid];

  const int nsub = nsub_p[0];

  // ---- weight fragments, pre-split into (hi, lo) bf16, in registers ----
  bf16x8 w1h[2][2], w1l[2][2], w2h[4], w2l[4];
#pragma unroll
  for (int nt = 0; nt < 2; ++nt) {
    const int col = (2*w + nt)*16 + c;
#pragma unroll
    for (int ks = 0; ks < 2; ++ks)
#pragma unroll
      for (int j = 0; j < 8; ++j) {
        float v = W1g[(ks*32 + g*8 + j)*HID + col];
        __bf16 hi = (__bf16)v;
        w1h[nt][ks][j] = hi;
        w1l[nt][ks][j] = (__bf16)(v - (float)hi);
      }
  }
#pragma unroll
  for (int i = 0; i < 4; ++i) {
    const int ks = 4*kh + i;
#pragma unroll
    for (int j = 0; j < 8; ++j) {
      float v = W2g[(ks*32 + g*8 + j)*DIM + (wq*16 + c)];
      __bf16 hi = (__bf16)v;
      w2h[i][j] = hi;
      w2l[i][j] = (__bf16)(v - (float)hi);
    }
  }
  float b1v[2];
#pragma unroll
  for (int nt = 0; nt < 2; ++nt) b1v[nt] = b1g[(2*w + nt)*16 + c];
  const float b2v = b2g[wq*16 + c];

  const int d_    = wq*16 + c;             // this lane's output dim
  const int physL = l ^ ((l >> 3) & 3);    // swizzled read chunk

  // swizzled element offsets for this lane's 4 (row,d) state slots
  int yoff[4];
#pragma unroll
  for (int s = 0; s < 4; ++s) {
    int row = 4*g + s;
    int lp  = row | (((d_ >> 3) & 3) << 4);
    int ph  = lp ^ ((lp >> 3) & 3);
    yoff[s] = (d_ >> 5)*512 + ph*8 + (d_ & 7);
  }
  int hoff[2][4];
#pragma unroll
  for (int nt = 0; nt < 2; ++nt) {
    int jcol = (2*w + nt)*16 + c;
#pragma unroll
    for (int r = 0; r < 4; ++r) {
      int row = 4*g + r;
      int lp  = row | (((jcol >> 3) & 3) << 4);
      int ph  = lp ^ ((lp >> 3) & 3);
      hoff[nt][r] = (jcol >> 5)*512 + ph*8 + (jcol & 7);
    }
  }

  // ---- initial state (replicated in wave pair); emit t=0 ----
  float y[4];
#pragma unroll
  for (int s = 0; s < 4; ++s) {
    int row = rowbase + 4*g + s;
    y[s] = y0[row*DIM + d_];
    if (hiW) out[(size_t)row*(T_SAVE*DIM) + d_] = y[s];
  }
  __syncthreads();   // ts_s ready

  float k1[4], k2[4], k3[4], k4[4], k5[4], k6[4], ysv[4];
#pragma unroll
  for (int s = 0; s < 4; ++s) ysv[s] = y[s];

  auto feval = [&](float (&kout)[4]) {
    // stage-input -> split bf16 -> fragment-ordered LDS (role-split stores)
#pragma unroll
    for (int s = 0; s < 4; ++s) {
      __bf16 hi = (__bf16)ysv[s];
      if (hiW) Yh[yoff[s]] = hi;
      else     Yl[yoff[s]] = (__bf16)(ysv[s] - (float)hi);
    }
    __syncthreads();                        // bar1: Y ready
    bf16x8 ah0 = *(const bf16x8*)&Yh[physL*8];
    bf16x8 ah1 = *(const bf16x8*)&Yh[512 + physL*8];
    bf16x8 al0 = *(const bf16x8*)&Yl[physL*8];
    bf16x8 al1 = *(const bf16x8*)&Yl[512 + physL*8];
    f32x4 acc[2];
#pragma unroll
    for (int nt = 0; nt < 2; ++nt) acc[nt] = f32x4{0.f,0.f,0.f,0.f};
#pragma unroll
    for (int nt = 0; nt < 2; ++nt) acc[nt] = MFMA_B16(ah0, w1h[nt][0], acc[nt]);
#pragma unroll
    for (int nt = 0; nt < 2; ++nt) acc[nt] = MFMA_B16(ah1, w1h[nt][1], acc[nt]);
#pragma unroll
    for (int nt = 0; nt < 2; ++nt) acc[nt] = MFMA_B16(ah0, w1l[nt][0], acc[nt]);
#pragma unroll
    for (int nt = 0; nt < 2; ++nt) acc[nt] = MFMA_B16(ah1, w1l[nt][1], acc[nt]);
#pragma unroll
    for (int nt = 0; nt < 2; ++nt) acc[nt] = MFMA_B16(al0, w1h[nt][0], acc[nt]);
#pragma unroll
    for (int nt = 0; nt < 2; ++nt) acc[nt] = MFMA_B16(al1, w1h[nt][1], acc[nt]);
    // tanh + bias, split, scatter to H fragment buffer
#pragma unroll
    for (int nt = 0; nt < 2; ++nt)
#pragma unroll
      for (int r = 0; r < 4; ++r) {
        float th = tanh_fast(acc[nt][r] + b1v[nt]);
        __bf16 hi = (__bf16)th;
        Hh[hoff[nt][r]] = hi;
        Hl[hoff[nt][r]] = (__bf16)(th - (float)hi);
      }
    __syncthreads();                        // bar2: H ready
    f32x4 a2[3];
#pragma unroll
    for (int i = 0; i < 3; ++i) a2[i] = f32x4{0.f,0.f,0.f,0.f};
#pragma unroll
    for (int i = 0; i < 4; ++i) {
      const int ks = 4*kh + i;
      bf16x8 ah = *(const bf16x8*)&Hh[ks*512 + physL*8];
      bf16x8 al = *(const bf16x8*)&Hl[ks*512 + physL*8];
      a2[0] = MFMA_B16(ah, w2h[i], a2[0]);
      a2[1] = MFMA_B16(ah, w2l[i], a2[1]);
      a2[2] = MFMA_B16(al, w2h[i], a2[2]);
    }
    f32x4 ps = (a2[0] + a2[1]) + a2[2];
    Pex[w*64 + l] = ps;
    __syncthreads();                        // bar3: partials ready
    f32x4 qs = Pex[(w ^ 4)*64 + l];
#pragma unroll
    for (int s = 0; s < 4; ++s)
      kout[s] = (ps[s] + qs[s]) + b2v;      // commutative -> identical in pair
  };

  for (int iv = 0; iv < T_SAVE-1; ++iv) {
    const float h = (ts_s[iv+1] - ts_s[iv]) / (float)nsub;
    for (int sub = 0; sub < nsub; ++sub) {
      feval(k1);
#pragma unroll
      for (int s = 0; s < 4; ++s) ysv[s] = fmaf(h, A21f*k1[s], y[s]);
      feval(k2);
#pragma unroll
      for (int s = 0; s < 4; ++s) {
        float t = fmaf(A32f, k2[s], A31f*k1[s]);
        ysv[s] = fmaf(h, t, y[s]);
      }
      feval(k3);
#pragma unroll
      for (int s = 0; s < 4; ++s) {
        float t = A41f*k1[s];
        t = fmaf(A42f, k2[s], t);
        t = fmaf(A43f, k3[s], t);
        ysv[s] = fmaf(h, t, y[s]);
      }
      feval(k4);
#pragma unroll
      for (int s = 0; s < 4; ++s) {
        float t = A51f*k1[s];
        t = fmaf(A52f, k2[s], t);
        t = fmaf(A53f, k3[s], t);
        t = fmaf(A54f, k4[s], t);
        ysv[s] = fmaf(h, t, y[s]);
      }
      feval(k5);
#pragma unroll
      for (int s = 0; s < 4; ++s) {
        float t = A61f*k1[s];
        t = fmaf(A62f, k2[s], t);
        t = fmaf(A63f, k3[s], t);
        t = fmaf(A64f, k4[s], t);
        t = fmaf(A65f, k5[s], t);
        ysv[s] = fmaf(h, t, y[s]);
      }
      feval(k6);
#pragma unroll
      for (int s = 0; s < 4; ++s) {
        float t = B1f*k1[s];
        t = fmaf(B2f, k2[s], t);
        t = fmaf(B3f, k3[s], t);
        t = fmaf(B4f, k4[s], t);
        t = fmaf(B5f, k5[s], t);
        t = fmaf(B6f, k6[s], t);
        y[s] = fmaf(h, t, y[s]);
        ysv[s] = y[s];
      }
    }
    if (hiW) {
#pragma unroll
      for (int s = 0; s < 4; ++s) {
        int row = rowbase + 4*g + s;
        out[(size_t)row*(T_SAVE*DIM) + (size_t)(iv+1)*DIM + d_] = y[s];
      }
    }
  }
}

extern "C" void kernel_launch(void* const* d_in, const int* in_sizes, int n_in,
                              void* d_out, int out_size, void* d_ws, size_t ws_size,
                              hipStream_t stream) {
  const float* y0 = (const float*)d_in[0];
  const float* ts = (const float*)d_in[1];
  const float* W1 = (const float*)d_in[2];
  const float* b1 = (const float*)d_in[3];
  const float* W2 = (const float*)d_in[4];
  const float* b2 = (const float*)d_in[5];
  const int* nsub = (const int*)d_in[6];
  float* out = (float*)d_out;

  const int Bnum = in_sizes[0] / DIM;       // 4096
  const int nblocks = Bnum / 16;            // 256 workgroups, one per CU
  node_tsit5_kernel<<<nblocks, 512, 0, stream>>>(y0, ts, W1, b1, W2, b2, nsub, out);
}